// Round 9
// baseline (105.164 us; speedup 1.0000x reference)
//
#include <hip/hip_runtime.h>

// Chamfer loss: x [B,N,D], y [B,M,D], D=3, fp32.
// dist[b,m,n] = ||x[b,n]-y[b,m]||^2
// row[b] = mean_n min_m dist ; col[b] = mean_m min_n dist
// out = mean_b max(row, col)
//
// R9: no-LDS main loop. Targets are wave-uniform -> read them through the
// SCALAR pipe (s_load_dwordx16 prefetch into SGPRs), not ds_read/VMEM.
//  K0: pack both point sets as float4 (x,y,z, 0.5*||p||^2)  [2 MB]; arm done.
//  K1: 1024 blocks (2 dir x 32 batch x 16 chunks), 256 thr, QPT=8.
//      8 queries/thread in VGPRs (coalesced float4 loads from packed),
//      loop 128 uniform targets from SGPRs: per 2 targets x 8 queries =
//      2 mov + 48 fma + 8 min3 (~3.6 VALU ops/pair), zero LDS, zero
//      hot-loop VMEM. Partial mins -> part[seg][chunk][query].
//  K2: 512 blocks: min over 16 chunks, finish dist = 2*(s + h_q),
//      block sums; last block (done counter) -> max(row,col) -> mean -> out.

#define BATCH   32
#define NPTS    2048
#define THREADS 256
#define QPT     8              // 256*8 = 2048 queries per block
#define TCH     16             // target chunks per (dir,batch)
#define TC      (NPTS / TCH)   // 128 targets per chunk
#define NSEG    (2 * BATCH)    // 64 segments
#define CBLK    8              // combine blocks per segment
#define NCOMB   (NSEG * CBLK)  // 512 combine blocks
#define NPTSTOT (2 * BATCH * NPTS)   // 131072 packed points

// packed[dir][b][i]: dir0 = y points (targets for row), dir1 = x points.
__global__ __launch_bounds__(THREADS) void chamfer_pack(
    const float* __restrict__ x, const float* __restrict__ y,
    float4* __restrict__ packed, unsigned* __restrict__ done)
{
    const int gid = blockIdx.x * THREADS + threadIdx.x;   // 0..131071
    if (gid == 0) *done = 0u;                             // arm K2's counter
    const int dir = gid >> 16;            // 65536 points per dir
    const int idx = gid & 0xFFFF;         // b*NPTS + i
    const float* src = (dir == 0 ? y : x);
    float px = src[3 * idx + 0];
    float py = src[3 * idx + 1];
    float pz = src[3 * idx + 2];
    packed[gid] = make_float4(px, py, pz, 0.5f * (px * px + py * py + pz * pz));
}

__global__ __launch_bounds__(THREADS) void chamfer_min(
    const float4* __restrict__ packed,
    float* __restrict__ part /* [NSEG][TCH][NPTS] */)
{
    const int blk   = blockIdx.x;      // 1024
    const int dir   = blk >> 9;
    const int r     = blk & 511;
    const int b     = r >> 4;
    const int chunk = r & 15;

    // Targets: uniform address stream -> scalar loads (SMEM).
    const float4* tq = packed + ((size_t)dir << 16) + b * NPTS + chunk * TC;
    // Queries: opposite set, per-lane float4 loads (coalesced).
    const float4* qq = packed + ((size_t)(1 - dir) << 16) + b * NPTS;

    float nqx[QPT], nqy[QPT], nqz[QPT], mn[QPT];
#pragma unroll
    for (int k = 0; k < QPT; ++k) {
        float4 qv = qq[threadIdx.x + k * THREADS];
        nqx[k] = -qv.x;
        nqy[k] = -qv.y;
        nqz[k] = -qv.z;
        mn[k]  = 3.4e38f;
    }

    // min over chunk targets of s = h_t - q.t  (dist = 2s + ||q||^2, monotone)
#pragma unroll 4
    for (int j = 0; j < TC; j += 2) {
        float4 a = tq[j];        // wave-uniform -> s_load into SGPRs
        float4 c = tq[j + 1];
#pragma unroll
        for (int k = 0; k < QPT; ++k) {
            float s0 = fmaf(nqz[k], a.z, fmaf(nqy[k], a.y, fmaf(nqx[k], a.x, a.w)));
            float s1 = fmaf(nqz[k], c.z, fmaf(nqy[k], c.y, fmaf(nqx[k], c.x, c.w)));
            mn[k] = fminf(fminf(mn[k], s0), s1);   // v_min3_f32
        }
    }

    // Plain coalesced partial writes — no init, no atomics.
    float* pbase = part + ((size_t)(dir * BATCH + b) * TCH + chunk) * NPTS;
#pragma unroll
    for (int k = 0; k < QPT; ++k)
        pbase[threadIdx.x + k * THREADS] = mn[k];
}

__global__ __launch_bounds__(THREADS) void chamfer_combine(
    const float4* __restrict__ packed,
    const float* __restrict__ part,
    float* __restrict__ blocksums /* [NCOMB] */,
    unsigned* __restrict__ done,
    float* __restrict__ out)
{
    __shared__ float wsum[THREADS / 64];
    __shared__ int flagLast;

    const int blk = blockIdx.x;        // 512 = NSEG * CBLK
    const int seg = blk >> 3;
    const int qc  = blk & 7;
    const int dir = seg >> 5;
    const int b   = seg & 31;
    const int qi  = qc * THREADS + threadIdx.x;

    // min over the 16 chunk partials (wave-coalesced strided loads)
    const float* p = part + (size_t)seg * TCH * NPTS + qi;
    float mn = p[0];
#pragma unroll
    for (int c = 1; c < TCH; ++c)
        mn = fminf(mn, p[(size_t)c * NPTS]);

    float4 qv = packed[((size_t)(1 - dir) << 16) + b * NPTS + qi];
    float d = 2.0f * (mn + qv.w);      // dist = 2s + ||q||^2 = 2(s + h_q)

    for (int off = 32; off > 0; off >>= 1)
        d += __shfl_down(d, off);
    if ((threadIdx.x & 63) == 0) wsum[threadIdx.x >> 6] = d;
    __syncthreads();

    if (threadIdx.x == 0) {
        float tot = wsum[0] + wsum[1] + wsum[2] + wsum[3];
        __hip_atomic_store(&blocksums[blk], tot, __ATOMIC_RELEASE,
                           __HIP_MEMORY_SCOPE_AGENT);
        unsigned old = __hip_atomic_fetch_add(done, 1u, __ATOMIC_ACQ_REL,
                                              __HIP_MEMORY_SCOPE_AGENT);
        flagLast = (old == (unsigned)(NCOMB - 1));
    }
    __syncthreads();
    if (!flagLast) return;

    // ---- last block: per-seg totals, max(row,col), mean ----
    if (threadIdx.x < 64) {
        const int lane = threadIdx.x;   // lane = seg
        float s = 0.0f;
#pragma unroll
        for (int i = 0; i < CBLK; ++i)
            s += __hip_atomic_load(&blocksums[lane * CBLK + i],
                                   __ATOMIC_ACQUIRE, __HIP_MEMORY_SCOPE_AGENT);
        // lane < 32: row(batch=lane) ; lane >= 32: col(batch=lane-32)
        float other = __shfl(s, lane + 32);
        float v = (lane < 32) ? fmaxf(s, other) * (1.0f / NPTS) : 0.0f;
        for (int off = 16; off > 0; off >>= 1)
            v += __shfl_down(v, off);
        if (lane == 0) out[0] = v * (1.0f / BATCH);
    }
}

extern "C" void kernel_launch(void* const* d_in, const int* in_sizes, int n_in,
                              void* d_out, int out_size, void* d_ws, size_t ws_size,
                              hipStream_t stream) {
    const float* x = (const float*)d_in[0];
    const float* y = (const float*)d_in[1];
    float* out = (float*)d_out;

    char* ws = (char*)d_ws;
    float*    part      = (float*)ws;                                  // 8 MB
    float4*   packed    = (float4*)(ws + (size_t)NSEG * TCH * NPTS * 4); // 2 MB
    float*    blocksums = (float*)(packed + NPTSTOT);                  // 2 KB
    unsigned* done      = (unsigned*)(blocksums + NCOMB);

    chamfer_pack<<<NPTSTOT / THREADS, THREADS, 0, stream>>>(x, y, packed, done);
    chamfer_min<<<2 * BATCH * TCH, THREADS, 0, stream>>>(packed, part);
    chamfer_combine<<<NCOMB, THREADS, 0, stream>>>(packed, part, blocksums, done, out);
}

// Round 10
// 86.794 us; speedup vs baseline: 1.2117x; 1.2117x over previous
//
#include <hip/hip_runtime.h>

// Chamfer loss: x [B,N,D], y [B,M,D], D=3, fp32.
// dist[b,m,n] = ||x[b,n]-y[b,m]||^2
// row[b] = mean_n min_m dist ; col[b] = mean_m min_n dist
// out = mean_b max(row, col)
//
// R10: R4 skeleton (measured best, 3 plain dispatches) with the LDS:VALU
// cycle ratio halved. Per-wave: each wave must read every target it scans
// (T ds_read_b128) while doing T*q*3.5 VALU instrs; at q=8 the per-CU LDS
// pipe is ~86% busy vs the VALU-bound runtime -> coupled stalls. q=16
// (128-thread blocks, 2048 queries/block) drops LDS to ~43%.
//  K1: 2048 blocks (2 dir x 32 batch x 32 chunks) x 128 thr, QPT=16.
//      8 blocks/CU = 4 waves/SIMD; launch_bounds(128,4) caps VGPR at 128.
//      Partial mins -> part[seg][chunk][query]. No atomics.
//  K2: 512 blocks x 256 thr: min over 32 chunks, finish dist, block sums.
//  K3: 1 block x 64: per-seg totals -> max(row,col) -> mean -> out.

#define BATCH   32
#define NPTS    2048
#define THREADS 128
#define QPT     16             // 128*16 = 2048 queries per block
#define TCH     32             // target chunks per (dir,batch)
#define TC      (NPTS / TCH)   // 64 targets per chunk
#define NSEG    (2 * BATCH)    // 64 segments
#define CTHREADS 256
#define CBLK    8              // combine blocks per segment
#define NCOMB   (NSEG * CBLK)  // 512 combine blocks

__global__ __launch_bounds__(THREADS, 4) void chamfer_min(
    const float* __restrict__ x, const float* __restrict__ y,
    float* __restrict__ part /* [NSEG][TCH][NPTS] */)
{
    __shared__ float4 t4[TC];   // (tx,ty,tz, 0.5*||t||^2) — 1 KB

    const int blk   = blockIdx.x;      // 2048
    const int dir   = blk >> 10;
    const int r     = blk & 1023;
    const int b     = r >> 5;
    const int chunk = r & 31;

    const float* q = (dir == 0 ? x : y) + (size_t)b * NPTS * 3;
    const float* t = (dir == 0 ? y : x) + (size_t)b * NPTS * 3;

    // Stage this chunk's 64 targets with precomputed h = 0.5*||t||^2.
    if (threadIdx.x < TC) {
        int jj = chunk * TC + threadIdx.x;
        float tx = t[3 * jj + 0];
        float ty = t[3 * jj + 1];
        float tz = t[3 * jj + 2];
        t4[threadIdx.x] = make_float4(tx, ty, tz, 0.5f * (tx * tx + ty * ty + tz * tz));
    }

    // 16 query points per thread (block covers all 2048 queries).
    float nqx[QPT], nqy[QPT], nqz[QPT], mn[QPT];
#pragma unroll
    for (int k = 0; k < QPT; ++k) {
        int qi = threadIdx.x + k * THREADS;
        nqx[k] = -q[3 * qi + 0];
        nqy[k] = -q[3 * qi + 1];
        nqz[k] = -q[3 * qi + 2];
        mn[k]  = 3.4e38f;
    }
    __syncthreads();

    // min over chunk targets of s = h_t - q.t  (dist = 2s + ||q||^2, monotone)
#pragma unroll 2
    for (int j = 0; j < TC; j += 2) {
        float4 a = t4[j];                 // wave-uniform -> broadcast
        float4 c = t4[j + 1];
#pragma unroll
        for (int k = 0; k < QPT; ++k) {
            float s0 = fmaf(nqz[k], a.z, fmaf(nqy[k], a.y, fmaf(nqx[k], a.x, a.w)));
            float s1 = fmaf(nqz[k], c.z, fmaf(nqy[k], c.y, fmaf(nqx[k], c.x, c.w)));
            mn[k] = fminf(fminf(mn[k], s0), s1);   // v_min3_f32
        }
    }

    // Plain coalesced partial writes — no init, no atomics.
    float* pbase = part + ((size_t)(dir * BATCH + b) * TCH + chunk) * NPTS;
#pragma unroll
    for (int k = 0; k < QPT; ++k)
        pbase[threadIdx.x + k * THREADS] = mn[k];
}

__global__ __launch_bounds__(CTHREADS) void chamfer_combine(
    const float* __restrict__ x, const float* __restrict__ y,
    const float* __restrict__ part,
    float* __restrict__ blocksums /* [NCOMB] */)
{
    __shared__ float wsum[CTHREADS / 64];

    const int blk = blockIdx.x;        // 512 = NSEG * CBLK
    const int seg = blk >> 3;
    const int qc  = blk & 7;
    const int dir = seg >> 5;
    const int b   = seg & 31;
    const int qi  = qc * CTHREADS + threadIdx.x;

    // min over the 32 chunk partials (wave-coalesced strided loads)
    const float* p = part + (size_t)seg * TCH * NPTS + qi;
    float mn = p[0];
#pragma unroll
    for (int c = 1; c < TCH; ++c)
        mn = fminf(mn, p[(size_t)c * NPTS]);

    const float* q = (dir == 0 ? x : y) + (size_t)b * NPTS * 3 + 3 * qi;
    float qx = q[0], qy = q[1], qz = q[2];
    float d = fmaf(2.0f, mn, qx * qx + qy * qy + qz * qz);

    for (int off = 32; off > 0; off >>= 1)
        d += __shfl_down(d, off);
    if ((threadIdx.x & 63) == 0) wsum[threadIdx.x >> 6] = d;
    __syncthreads();
    if (threadIdx.x == 0)
        blocksums[blk] = wsum[0] + wsum[1] + wsum[2] + wsum[3];
}

__global__ void chamfer_finalize(const float* __restrict__ blocksums,
                                 float* __restrict__ out)
{
    const int lane = threadIdx.x;   // 64 threads: lane = seg
    float s = 0.0f;
#pragma unroll
    for (int i = 0; i < CBLK; ++i)
        s += blocksums[lane * CBLK + i];
    // lane < 32: row for batch=lane ; lane >= 32: col for batch=lane-32
    float other = __shfl(s, lane + 32);      // valid where lane < 32
    float v = (lane < 32) ? fmaxf(s, other) * (1.0f / NPTS) : 0.0f;
    for (int off = 16; off > 0; off >>= 1)
        v += __shfl_down(v, off);
    if (lane == 0) out[0] = v * (1.0f / BATCH);
}

extern "C" void kernel_launch(void* const* d_in, const int* in_sizes, int n_in,
                              void* d_out, int out_size, void* d_ws, size_t ws_size,
                              hipStream_t stream) {
    const float* x = (const float*)d_in[0];
    const float* y = (const float*)d_in[1];
    float* out = (float*)d_out;

    float* part      = (float*)d_ws;                               // 16 MB
    float* blocksums = part + (size_t)NSEG * TCH * NPTS;           // 2 KB

    chamfer_min<<<2 * BATCH * TCH, THREADS, 0, stream>>>(x, y, part);
    chamfer_combine<<<NCOMB, CTHREADS, 0, stream>>>(x, y, part, blocksums);
    chamfer_finalize<<<1, 64, 0, stream>>>(blocksums, out);
}

// Round 11
// 84.209 us; speedup vs baseline: 1.2488x; 1.0307x over previous
//
#include <hip/hip_runtime.h>

// Chamfer loss: x [B,N,D], y [B,M,D], D=3, fp32.
// dist[b,m,n] = ||x[b,n]-y[b,m]||^2
// row[b] = mean_n min_m dist ; col[b] = mean_m min_n dist
// out = mean_b max(row, col)
//
// R11: SYMMETRIC FUSION — compute each distance ONCE, serve both directions.
// c(n,m) = h_x[n] + h_y[m] - x.y  (dist = 2c; h = 0.5*||p||^2).
//  K1: 2048 blocks (32 batch x 64 y-chunks) x 128 thr. Each thread owns 16
//      x-queries (block covers ALL 2048 x) and scans 32 y-targets from LDS.
//      Row-mins (over m) -> part[b][chunk][n] (16 MB, combined in K2).
//      Col-mins (over n) are COMPLETE per block (it sees all x): per-thread
//      partials -> padded LDS -> tree reduce -> colmin[b][m] (256 KB).
//      2.5 VALU instr/pair-direction (was 3.5), half the ds_reads/pair-dir.
//  K2: 256 row blocks (min over 64 chunks, d=2c, block sums)
//      + 32 col blocks (sum 2*colmin per batch).
//  K3: 1 block x 64: per-batch row/col means -> max -> mean -> out.

#define BATCH   32
#define NPTS    2048
#define THREADS 128
#define QPT     16             // 128*16 = 2048 x-queries per block
#define TCH     64             // y-chunks per batch
#define TC      (NPTS / TCH)   // 32 y-targets per chunk
#define NROWB   (BATCH * 8)    // 256 row-combine blocks
#define NCOLB   BATCH          // 32 col-sum blocks

__global__ __launch_bounds__(THREADS, 4) void chamfer_min(
    const float* __restrict__ x, const float* __restrict__ y,
    float* __restrict__ part    /* [BATCH][TCH][NPTS] */,
    float* __restrict__ colmin  /* [BATCH][NPTS] */)
{
    __shared__ float4 t4[TC];                 // (ty0,ty1,ty2, h_y) — 512 B
    __shared__ float colLds[THREADS][TC + 1]; // +1 pad: conflict-free — 16.9 KB
    __shared__ float cmPart[4][TC + 1];       // 528 B

    const int blk   = blockIdx.x;      // 2048
    const int b     = blk >> 6;
    const int chunk = blk & 63;

    const float* qp = x + (size_t)b * NPTS * 3;
    const float* tp = y + (size_t)b * NPTS * 3;

    // Stage this chunk's 32 y-targets with h_y = 0.5*||y||^2.
    if (threadIdx.x < TC) {
        int jj = chunk * TC + threadIdx.x;
        float ty0 = tp[3 * jj + 0];
        float ty1 = tp[3 * jj + 1];
        float ty2 = tp[3 * jj + 2];
        t4[threadIdx.x] = make_float4(ty0, ty1, ty2,
                                      0.5f * (ty0 * ty0 + ty1 * ty1 + ty2 * ty2));
    }

    // 16 x-queries per thread: negated coords + h_x.
    float nqx[QPT], nqy[QPT], nqz[QPT], hx[QPT], mn[QPT];
#pragma unroll
    for (int k = 0; k < QPT; ++k) {
        int qi = threadIdx.x + k * THREADS;
        float qx = qp[3 * qi + 0];
        float qy = qp[3 * qi + 1];
        float qz = qp[3 * qi + 2];
        nqx[k] = -qx;
        nqy[k] = -qy;
        nqz[k] = -qz;
        hx[k]  = 0.5f * (qx * qx + qy * qy + qz * qz);
        mn[k]  = 3.4e38f;
    }
    __syncthreads();

    // c(n,m) = h_x + h_y - x.y ; dist = 2c. Row-min in regs, col-partial to LDS.
#pragma unroll 2
    for (int j = 0; j < TC; j += 2) {
        float4 a = t4[j];                 // wave-uniform -> broadcast
        float4 c4 = t4[j + 1];
        float colA = 3.4e38f, colB = 3.4e38f;
#pragma unroll
        for (int k = 0; k < QPT; k += 2) {
            float Wa0 = a.w  + hx[k],     Wb0 = c4.w + hx[k];
            float Wa1 = a.w  + hx[k + 1], Wb1 = c4.w + hx[k + 1];
            float s0 = fmaf(nqz[k], a.z, fmaf(nqy[k], a.y, fmaf(nqx[k], a.x, Wa0)));
            float s1 = fmaf(nqz[k], c4.z, fmaf(nqy[k], c4.y, fmaf(nqx[k], c4.x, Wb0)));
            float t0 = fmaf(nqz[k+1], a.z, fmaf(nqy[k+1], a.y, fmaf(nqx[k+1], a.x, Wa1)));
            float t1 = fmaf(nqz[k+1], c4.z, fmaf(nqy[k+1], c4.y, fmaf(nqx[k+1], c4.x, Wb1)));
            mn[k]     = fminf(fminf(mn[k], s0), s1);       // v_min3
            mn[k + 1] = fminf(fminf(mn[k + 1], t0), t1);   // v_min3
            colA = fminf(fminf(colA, s0), t0);             // v_min3
            colB = fminf(fminf(colB, s1), t1);             // v_min3
        }
        colLds[threadIdx.x][j]     = colA;
        colLds[threadIdx.x][j + 1] = colB;
    }
    __syncthreads();

    // Col reduce: 4 groups of 32 rows, one (group, target) per thread.
    {
        const int g = threadIdx.x >> 5;    // 0..3
        const int j = threadIdx.x & 31;    // target within chunk
        float cp = 3.4e38f;
#pragma unroll
        for (int i = 0; i < 32; ++i)
            cp = fminf(cp, colLds[g * 32 + i][j]);
        cmPart[g][j] = cp;
    }
    __syncthreads();
    if (threadIdx.x < TC) {
        const int j = threadIdx.x;
        float cm = fminf(fminf(cmPart[0][j], cmPart[1][j]),
                         fminf(cmPart[2][j], cmPart[3][j]));
        colmin[(size_t)b * NPTS + chunk * TC + j] = cm;   // complete col-min
    }

    // Row partials: plain coalesced writes — no init, no atomics.
    float* pbase = part + ((size_t)b * TCH + chunk) * NPTS;
#pragma unroll
    for (int k = 0; k < QPT; ++k)
        pbase[threadIdx.x + k * THREADS] = mn[k];
}

#define CTHREADS 256

__global__ __launch_bounds__(CTHREADS) void chamfer_combine(
    const float* __restrict__ part,
    const float* __restrict__ colmin,
    float* __restrict__ blocksums /* [NROWB + NCOLB] */)
{
    __shared__ float wsum[CTHREADS / 64];

    const int blk = blockIdx.x;        // 288 = NROWB + NCOLB
    float d;

    if (blk < NROWB) {
        // Row: min over 64 chunks for one query, d = 2c.
        const int b  = blk >> 3;
        const int qc = blk & 7;
        const int qi = qc * CTHREADS + threadIdx.x;
        const float* p = part + (size_t)b * TCH * NPTS + qi;
        float mn = p[0];
#pragma unroll
        for (int c = 1; c < TCH; ++c)
            mn = fminf(mn, p[(size_t)c * NPTS]);
        d = 2.0f * mn;
    } else {
        // Col: sum 2*colmin over this batch (8 values per thread).
        const int b = blk - NROWB;
        const float* p = colmin + (size_t)b * NPTS;
        float s = 0.0f;
#pragma unroll
        for (int i = 0; i < 8; ++i)
            s += p[threadIdx.x + i * CTHREADS];
        d = 2.0f * s;
    }

    for (int off = 32; off > 0; off >>= 1)
        d += __shfl_down(d, off);
    if ((threadIdx.x & 63) == 0) wsum[threadIdx.x >> 6] = d;
    __syncthreads();
    if (threadIdx.x == 0)
        blocksums[blk] = wsum[0] + wsum[1] + wsum[2] + wsum[3];
}

__global__ void chamfer_finalize(const float* __restrict__ blocksums,
                                 float* __restrict__ out)
{
    const int lane = threadIdx.x;   // 64 threads; lanes >= 32 contribute 0
    float v = 0.0f;
    if (lane < BATCH) {
        float rs = 0.0f;
#pragma unroll
        for (int i = 0; i < 8; ++i)
            rs += blocksums[lane * 8 + i];
        float cs = blocksums[NROWB + lane];
        v = fmaxf(rs, cs) * (1.0f / NPTS);
    }
    for (int off = 32; off > 0; off >>= 1)
        v += __shfl_down(v, off);
    if (lane == 0) out[0] = v * (1.0f / BATCH);
}

extern "C" void kernel_launch(void* const* d_in, const int* in_sizes, int n_in,
                              void* d_out, int out_size, void* d_ws, size_t ws_size,
                              hipStream_t stream) {
    const float* x = (const float*)d_in[0];
    const float* y = (const float*)d_in[1];
    float* out = (float*)d_out;

    float* part      = (float*)d_ws;                          // 16 MB
    float* colmin    = part + (size_t)BATCH * TCH * NPTS;     // 256 KB
    float* blocksums = colmin + (size_t)BATCH * NPTS;         // ~1.2 KB

    chamfer_min<<<BATCH * TCH, THREADS, 0, stream>>>(x, y, part, colmin);
    chamfer_combine<<<NROWB + NCOLB, CTHREADS, 0, stream>>>(part, colmin, blocksums);
    chamfer_finalize<<<1, 64, 0, stream>>>(blocksums, out);
}